// Round 8
// baseline (241.429 us; speedup 1.0000x reference)
//
#include <hip/hip_runtime.h>

// CTC batch cost (keras ctc_batch_cost semantics). B=512,T=512,C=128,L=32,S=65.
// R8: fwd and bwd chains in SEPARATE BLOCKS (2B blocks, 4 waves/CU) so one
// chain's s_waitcnt stalls don't block the other (R7: both chains in one wave
// -> zero overlap, 92us). Loads: ONE per lane per row (q_t[class(lane)]);
// neighbor classes' probs are produced by shfl at refill time (lane l needs
// q[class(l-i)] = what lane l-i loaded) -> 4 loads/group instead of 17/28,
// prefetch buffers small enough for the compiler to keep 3 groups in flight.
// Merge: second-finishing block per batch element (device-scope atomic flag)
// does the 65-term logsumexp. Flags zeroed via capture-safe hipMemsetAsync.

#define EPSF 1e-7f
#define NEGB (-1e30f)

constexpr int T_ = 512;
constexpr int C_ = 128;
constexpr int L_ = 32;

__device__ __forceinline__ float gatb(const float* r, int boff) {
    return *(const float*)((const char*)r + boff);
}

__device__ __forceinline__ void apply_scale(const float* s, float& x, float& y, int& e) {
    float t[8];
#pragma unroll
    for (int i = 0; i < 8; ++i) t[i] = fmaxf(s[i], s[i + 8]);
#pragma unroll
    for (int i = 0; i < 4; ++i) t[i] = fmaxf(t[i], t[i + 4]);
    float m = fmaxf(fmaxf(t[0], t[1]), fmaxf(t[2], t[3]));
    m = fmaxf(m, 9.094947e-13f);                     // 2^-40 guard
    int be = (int)(__float_as_uint(m) >> 23);        // biased exponent
    be = (be < 67) ? 67 : ((be > 187) ? 187 : be);   // step in [2^-60, 2^60]
    e += be - 127;                                   // target 2^0
    const float inv = __uint_as_float((unsigned)(254 - be) << 23);  // exact pow2
    x *= inv; y *= inv;
}

__launch_bounds__(64)
__global__ void ctc_chain_kernel(const int* __restrict__ y_true,
                                 const float* __restrict__ y_pred,
                                 float* __restrict__ out,
                                 float* __restrict__ data,
                                 int* __restrict__ flags,
                                 int B) {
    const int blk  = blockIdx.x;
    const bool fwd = (blk < B);
    const int bidx = fwd ? blk : blk - B;
    const int lane = threadIdx.x;
    const float* bb  = y_pred + (size_t)bidx * T_ * C_;
    const int*   lbl = y_true + bidx * L_;
    float* rec = data + (size_t)bidx * 132;

    if (fwd) {
        // ---- forward: alpha over rows 1..256, 64 groups of 4 ----
        int cf0;
        {
            int c = C_ - 1;
            if (lane & 1) c = lbl[(lane - 1) >> 1];
            cf0 = c * 4;
        }
        float sg[7], msk[9];
#pragma unroll
        for (int i = 0; i < 7; ++i) {
            const int v = lane - i;
            float s = 0.f;
            if (v >= 3 && (v & 1) && lbl[(v - 1) >> 1] != lbl[((v - 1) >> 1) - 1]) s = 1.f;
            sg[i] = s;
        }
#pragma unroll
        for (int i = 0; i < 9; ++i) msk[i] = (lane >= i) ? 1.f : 0.f;

        float a   = (lane < 2) ? (gatb(bb, cf0) + EPSF) : 0.f;
        float a64 = 0.f;
        int   ef  = 0;
        float smp[16];
        float r0[4], r1[4], r2[4], e0[17], e1[17];

        auto loadg = [&](float (&rv)[4], int g) {
            const float* base = bb + (size_t)(1 + 4 * g) * C_;
#pragma unroll
            for (int j = 0; j < 4; ++j) rv[j] = gatb(base + (size_t)j * C_, cf0);
        };
        auto expand = [&](const float (&rv)[4], float (&e)[17]) {
            e[0] = rv[0];
#pragma unroll
            for (int i = 1; i <= 6; ++i) e[i] = __shfl_up(rv[0], i);
            e[7] = rv[1];
#pragma unroll
            for (int i = 1; i <= 4; ++i) e[7 + i] = __shfl_up(rv[1], i);
            e[12] = rv[2];
            e[13] = __shfl_up(rv[2], 1);
            e[14] = __shfl_up(rv[2], 2);
            e[15] = rv[3];
            e[16] = __shfl_up(rv[3], 1);
        };
        auto sample = [&]() {
#pragma unroll
            for (int i = 0; i < 16; ++i) smp[i] = __shfl(a, 4 * i + 3);
        };
        auto fgroup4 = [&](const float (&Qk)[17]) {
            float A[9];
            A[0] = a;
#pragma unroll
            for (int i = 1; i <= 8; ++i) A[i] = __shfl_up(a, i) * msk[i];
            float Bt[7];
#pragma unroll
            for (int i = 0; i <= 6; ++i)
                Bt[i] = (A[i] + A[i + 1] + sg[i] * A[i + 2]) * (Qk[i] + EPSF);
            float Cc[5];
#pragma unroll
            for (int i = 0; i <= 4; ++i)
                Cc[i] = (Bt[i] + Bt[i + 1] + sg[i] * Bt[i + 2]) * (Qk[7 + i] + EPSF);
            float D[3];
#pragma unroll
            for (int i = 0; i <= 2; ++i)
                D[i] = (Cc[i] + Cc[i + 1] + sg[i] * Cc[i + 2]) * (Qk[12 + i] + EPSF);
            float z = a64;
            z = (z + A[0])  * (Qk[1]  + EPSF);
            z = (z + Bt[0]) * (Qk[8]  + EPSF);
            z = (z + Cc[0]) * (Qk[13] + EPSF);
            z = (z + D[0])  * (Qk[16] + EPSF);
            a64 = z;
            a = (D[0] + D[1] + sg[0] * D[2]) * (Qk[15] + EPSF);
        };

        loadg(r0, 0); loadg(r1, 1); loadg(r2, 2);
        expand(r0, e0);
        sample();
        for (int t0 = 0; t0 < 60; t0 += 6) {
            fgroup4(e0); sample();                     expand(r1, e1); loadg(r0, t0 + 3);
            fgroup4(e1); apply_scale(smp, a, a64, ef); expand(r2, e0); loadg(r1, t0 + 4);
            fgroup4(e0); sample();                     expand(r0, e1); loadg(r2, t0 + 5);
            fgroup4(e1); apply_scale(smp, a, a64, ef); expand(r1, e0); loadg(r0, t0 + 6);
            fgroup4(e0); sample();                     expand(r2, e1); loadg(r1, t0 + 7);
            fgroup4(e1); apply_scale(smp, a, a64, ef); expand(r0, e0); loadg(r2, t0 + 8);
        }
        // tail: groups 60..63 (r0=g60 already expanded into e0; r1=g61, r2=g62)
        fgroup4(e0); sample();                     expand(r1, e1); loadg(r0, 63);
        fgroup4(e1); apply_scale(smp, a, a64, ef); expand(r2, e0);
        fgroup4(e0); sample();                     expand(r0, e1);
        fgroup4(e1); apply_scale(smp, a, a64, ef);

        rec[lane] = a;
        if (lane == 63) rec[64] = a64;
        if (lane == 0)  rec[65] = (float)ef;
    } else {
        // ---- backward: beta over rows 511..257 (63 groups + 3 singles) ----
        int cb0;
        {
            const int u = lane + 1;
            int c = C_ - 1;
            if (u & 1) c = lbl[(u - 1) >> 1];
            cb0 = c * 4;
        }
        float gd[7], mdn[9];
#pragma unroll
        for (int i = 0; i < 9; ++i) mdn[i] = (lane + i <= 63) ? 1.f : 0.f;
#pragma unroll
        for (int i = 0; i < 7; ++i) {
            const int v = lane + i + 3;
            float g = 0.f;
            if (v <= 64 && (v & 1) && lbl[(v - 1) >> 1] != lbl[((v - 1) >> 1) - 1]) g = 1.f;
            gd[i] = g;
        }
        float b  = (lane >= 62) ? 1.f : 0.f;
        float b0 = 0.f;
        int   eb = 0;
        float smp[16];
        float r0[4], r1[4], r2[4], e0[28], e1[28];

        auto loadg = [&](float (&rv)[4], int g) {
            const float* r3 = bb + (size_t)(511 - 4 * g) * C_;
#pragma unroll
            for (int j = 0; j < 4; ++j) rv[j] = gatb(r3 - (size_t)j * C_, cb0);
        };
        auto expand = [&](const float (&rv)[4], float (&e)[28]) {
            e[0] = rv[0];
#pragma unroll
            for (int i = 1; i <= 8; ++i) e[i] = __shfl_down(rv[0], i);
            e[9] = rv[1];
#pragma unroll
            for (int i = 1; i <= 6; ++i) e[9 + i] = __shfl_down(rv[1], i);
            e[16] = rv[2];
#pragma unroll
            for (int i = 1; i <= 4; ++i) e[16 + i] = __shfl_down(rv[2], i);
            e[21] = rv[3];
            e[22] = __shfl_down(rv[3], 1);
            e[23] = __shfl_down(rv[3], 2);
            e[24] = __shfl(rv[0], 63);   // blank prob per row (class(64)=blank)
            e[25] = __shfl(rv[1], 63);
            e[26] = __shfl(rv[2], 63);
            e[27] = __shfl(rv[3], 63);
        };
        auto sample = [&]() {
#pragma unroll
            for (int i = 0; i < 16; ++i) smp[i] = __shfl(b, 4 * i + 3);
        };
        auto bgroup4 = [&](const float (&Qk)[28]) {
            float BA[9];
            BA[0] = b;
#pragma unroll
            for (int i = 1; i <= 8; ++i) BA[i] = __shfl_down(b, i) * mdn[i];
            float G[9];
#pragma unroll
            for (int i = 0; i <= 8; ++i) G[i] = BA[i] * (Qk[i] + EPSF);
            float X[7];
#pragma unroll
            for (int i = 0; i <= 6; ++i) X[i] = G[i] + G[i + 1] + gd[i] * G[i + 2];
            float G2[7];
#pragma unroll
            for (int i = 0; i <= 6; ++i) G2[i] = X[i] * (Qk[9 + i] + EPSF);
            float X2[5];
#pragma unroll
            for (int i = 0; i <= 4; ++i) X2[i] = G2[i] + G2[i + 1] + gd[i] * G2[i + 2];
            float G3[5];
#pragma unroll
            for (int i = 0; i <= 4; ++i) G3[i] = X2[i] * (Qk[16 + i] + EPSF);
            float X3[3];
#pragma unroll
            for (int i = 0; i <= 2; ++i) X3[i] = G3[i] + G3[i + 1] + gd[i] * G3[i + 2];
            float G4[3];
#pragma unroll
            for (int i = 0; i <= 2; ++i) G4[i] = X3[i] * (Qk[21 + i] + EPSF);
            float z = b0;
            z = (Qk[24] + EPSF) * z + G[0];
            z = (Qk[25] + EPSF) * z + G2[0];
            z = (Qk[26] + EPSF) * z + G3[0];
            z = (Qk[27] + EPSF) * z + G4[0];
            b0 = z;
            b = G4[0] + G4[1] + gd[0] * G4[2];
        };

        loadg(r0, 0); loadg(r1, 1); loadg(r2, 2);
        expand(r0, e0);
        sample();
        for (int t0 = 0; t0 < 60; t0 += 6) {
            bgroup4(e0); sample();                    expand(r1, e1); loadg(r0, t0 + 3);
            bgroup4(e1); apply_scale(smp, b, b0, eb); expand(r2, e0); loadg(r1, t0 + 4);
            bgroup4(e0); sample();                    expand(r0, e1); loadg(r2, t0 + 5);
            bgroup4(e1); apply_scale(smp, b, b0, eb); expand(r1, e0); loadg(r0, t0 + 6);
            bgroup4(e0); sample();                    expand(r2, e1); loadg(r1, t0 + 7);
            bgroup4(e1); apply_scale(smp, b, b0, eb); expand(r0, e0); loadg(r2, t0 + 8);
        }
        // tail: groups 60..62
        bgroup4(e0); sample();                    expand(r1, e1);
        bgroup4(e1); apply_scale(smp, b, b0, eb); expand(r2, e0);
        bgroup4(e0);
        // singles: rows 259, 258, 257 -> beta_256
        float qv[3];
        qv[0] = gatb(bb + (size_t)259 * C_, cb0);
        qv[1] = gatb(bb + (size_t)258 * C_, cb0);
        qv[2] = gatb(bb + (size_t)257 * C_, cb0);
#pragma unroll
        for (int r = 0; r < 3; ++r) {
            const float q0 = qv[r] + EPSF;
            const float q1 = __shfl_down(qv[r], 1) + EPSF;
            const float q2 = __shfl_down(qv[r], 2) + EPSF;
            const float qb = __shfl(qv[r], 63) + EPSF;
            const float g0 = b * q0;
            const float g1 = __shfl_down(b, 1) * mdn[1] * q1;
            const float g2 = __shfl_down(b, 2) * mdn[2] * q2;
            b0 = qb * b0 + g0;
            b  = g0 + g1 + gd[0] * g2;
        }

        rec[66 + lane + 1] = b;
        if (lane == 0) { rec[66] = b0; rec[66 + 65] = (float)eb; }
    }

    // ---- cross-block merge: second finisher does the logsumexp ----
    __threadfence();
    int old = 0;
    if (lane == 0) old = atomicAdd(&flags[bidx], 1);
    old = __shfl(old, 0);
    if (old == 1) {
        __threadfence();
        const float* Av = data + (size_t)bidx * 132;
        const float* Bv = Av + 66;
        auto lg = [](float v) { return (v > 0.f) ? __logf(v) : NEGB; };
        float t1 = lg(Av[lane]) + lg(Bv[lane]);                          // s = lane
        float t2 = (lane == 63) ? (lg(Av[64]) + lg(Bv[64])) : NEGB;       // s = 64
        float wmax = fmaxf(t1, t2);
#pragma unroll
        for (int off = 1; off < 64; off <<= 1) wmax = fmaxf(wmax, __shfl_xor(wmax, off));
        float p = ((t1 > -1e29f) ? __expf(t1 - wmax) : 0.f)
                + ((t2 > -1e29f) ? __expf(t2 - wmax) : 0.f);
#pragma unroll
        for (int off = 1; off < 64; off <<= 1) p += __shfl_xor(p, off);
        if (lane == 0) {
            const float esum = Av[65] + Bv[65];
            out[bidx] = -(wmax + __logf(p) + esum * 0.6931471805599453f);
        }
    }
}

extern "C" void kernel_launch(void* const* d_in, const int* in_sizes, int n_in,
                              void* d_out, int out_size, void* d_ws, size_t ws_size,
                              hipStream_t stream) {
    const int*   y_true = (const int*)d_in[0];
    const float* y_pred = (const float*)d_in[1];
    float*       out    = (float*)d_out;
    const int B = out_size;   // 512

    int*   flags = (int*)d_ws;
    float* data  = (float*)((char*)d_ws + 4096);   // B*132 floats

    hipMemsetAsync(flags, 0, B * sizeof(int), stream);
    ctc_chain_kernel<<<2 * B, 64, 0, stream>>>(y_true, y_pred, out, data, flags, B);
}